// Round 4
// baseline (13.471 us; speedup 1.0000x reference)
//
#include <hip/hip_runtime.h>
#include <hip/hip_bf16.h>

// Embedding gather with OOV handling.
// out[r][d] = (idx[r] >= VOCAB) ? oov[d] : emb[idx[r]][d]
// D = 200 floats = 50 float4 per row; rows are 800B => 16B aligned.
//
// R4: drop __builtin_nontemporal_store (A/B vs R2's 11.87us, same ELEMS=4).
// Theory: NT stores bypass L2/L3 and force the 26.2MB write stream to drain
// to HBM in the kernel tail (~3.8us serialized). Cached stores complete at
// L2 (output fits 32MB aggregate) and write back during the next replay.
// ELEMS=8 was neutral vs 4 (12.00 vs 11.87) -> MLP is saturated at 4.

typedef float f32x4 __attribute__((ext_vector_type(4)));

#define ELEMS 4
#define BLOCK 256

__global__ void embed_gather_kernel(const int* __restrict__ indices,
                                    const f32x4* __restrict__ emb,
                                    const f32x4* __restrict__ oov,
                                    f32x4* __restrict__ out,
                                    int n_vec,      // total float4 elements in output
                                    int vocab) {
    int base = blockIdx.x * (BLOCK * ELEMS) + threadIdx.x;

    int   idx[ELEMS];
    int   off[ELEMS];
    f32x4 val[ELEMS];

    // Phase 1: issue all index loads (independent, L1-hot broadcast)
    #pragma unroll
    for (int k = 0; k < ELEMS; ++k) {
        int i = base + k * BLOCK;
        int ii = (i < n_vec) ? i : 0;
        int row = ii / 50;          // magic-mul, cheap
        off[k] = ii - row * 50;
        idx[k] = indices[row];
    }

    // Phase 2: issue all gather loads (independent -> 4 outstanding vmem ops)
    #pragma unroll
    for (int k = 0; k < ELEMS; ++k) {
        const f32x4* src = (idx[k] >= vocab)
                         ? (oov + off[k])
                         : (emb + (long long)idx[k] * 50 + off[k]);
        val[k] = *src;
    }

    // Phase 3: cached stores (complete at L2; writeback overlaps next replay)
    #pragma unroll
    for (int k = 0; k < ELEMS; ++k) {
        int i = base + k * BLOCK;
        if (i < n_vec) {
            out[i] = val[k];
        }
    }
}

extern "C" void kernel_launch(void* const* d_in, const int* in_sizes, int n_in,
                              void* d_out, int out_size, void* d_ws, size_t ws_size,
                              hipStream_t stream) {
    const int*   indices = (const int*)d_in[0];
    const float* emb     = (const float*)d_in[1];
    const float* oov     = (const float*)d_in[2];
    float*       out     = (float*)d_out;

    const int D      = in_sizes[2];            // 200
    const int vocab  = in_sizes[1] / D;        // 100000
    const int n_vec  = out_size / 4;           // float4 count

    const int grid = (n_vec + BLOCK * ELEMS - 1) / (BLOCK * ELEMS);
    embed_gather_kernel<<<grid, BLOCK, 0, stream>>>(
        indices,
        (const f32x4*)emb,
        (const f32x4*)oov,
        (f32x4*)out,
        n_vec, vocab);
}